// Round 5
// baseline (331.997 us; speedup 1.0000x reference)
//
#include <hip/hip_runtime.h>

// Multi-hot encode: out[n, t, x[n, t, f]] = 1.0, everything else 0.
// x: [32, 512, 10] int32, out: [32, 512, 5000] fp32 (~328 MB written/call).
//
// R5: zero via hipMemsetAsync (the rocclr fillBufferAligned path — measured
// 6.2 TB/s on this exact buffer in every profile so far, ~53 us for 328 MB),
// then a minimal scatter kernel sets the 163,840 ones (10.5 MB of touched
// cache lines, ~10-20 us). Stream order serializes memset -> scatter.
// This A/Bs my hand-written fill kernels (all stuck ~2.7 TB/s effective)
// against the known-fast fill path.

#define NUM_TOKENS 5000
#define NFEAT 10

__global__ __launch_bounds__(256) void tenhot_scatter(const int* __restrict__ x,
                                                      float* __restrict__ out,
                                                      int n_idx) {
    const int gid = blockIdx.x * 256 + threadIdx.x;
    if (gid < n_idx) {
        const int idx = x[gid];            // coalesced index load
        const int row = gid / NFEAT;       // magic-mul division
        out[(size_t)row * NUM_TOKENS + idx] = 1.0f;
    }
}

extern "C" void kernel_launch(void* const* d_in, const int* in_sizes, int n_in,
                              void* d_out, int out_size, void* d_ws, size_t ws_size,
                              hipStream_t stream) {
    const int* x = (const int*)d_in[0];
    float* out = (float*)d_out;
    const int n_idx = in_sizes[0];  // 32*512*10 = 163840

    // Zero the output with the device fill path (graph-capturable).
    hipMemsetAsync(out, 0, (size_t)out_size * sizeof(float), stream);

    // Scatter the ones.
    const int blocks = (n_idx + 255) / 256;  // 640
    tenhot_scatter<<<blocks, 256, 0, stream>>>(x, out, n_idx);
}